// Round 3
// baseline (119.541 us; speedup 1.0000x reference)
//
#include <hip/hip_runtime.h>

// SLAYER 2-layer SNN, MI355X. Round-13 (R2): wave-parallel scan phases.
// R1 post-mortem: conv issue cut (-40% instr) bought only 1.7us -> L1/L2 are
// NOT issue-bound. Historical VALUBusy <=14%: latency-bound. Diagnosis: the
// scan phase runs on 1 wave of 4 (tid<64), a 64-step serial chain (~20cyc/t
// loop-carried ur->vr->m->s->ur) while 3/4 of the block idles at a barrier.
// Fix: block = 16 rows x 16 cols; each wave owns 4 rows END-TO-END: conv
// (bit->float hoisted per window row, shared by 5 output rows), its own
// 64-px scan, its own transpose/store. 100% wave utilization in every phase;
// grid 2304 -> 576; window loads 2.5x fewer per row.
// Bitwise: all float chains identical to r8-r12 (conv per-row j-ascending,
// ((l0+l1)+(l2+l3))+l4; scan ops untouched; lut3 untouched). Only the
// thread->pixel mapping and LDS layout changed.
//   KA: floats -> bitT[y][xw][t]  (1152 blocks, streaming, proven)
//   L1: 8 window rows/wave -> hoisted VALU conv (4 rows) -> ct[wv] LDS ->
//       per-wave scan1 -> per-wave transpose -> s1h    [576 blocks, 68.6KB]
//   L2: 6 window rows/wave -> patterns -> ptile[wv] LDS -> per-wave scan2
//       (lut3[512]) -> coalesced float out             [576 blocks, 37.9KB]
// absmax == 0 every round so far.

#define HH   192
#define WW   192
#define NIMG 4
#define TT   64
#define NT   256
#define XW   6     // uint32 x-words per image row
#define XH   12    // 16-bit x-halfwords per image row

#define E_D 2.718281828459045
static constexpr float D1  = (float)0.36787944117144233;   // exp(-1/1)
static constexpr float CP1 = (float)(E_D);
static constexpr float DR1 = (float)0.36787944117144233;
static constexpr float CR1 = (float)(-30.0 * E_D);
static constexpr float D2  = (float)0.6065306597126334;    // exp(-1/2)
static constexpr float CP2 = (float)(E_D * 0.5);
static constexpr float DR2 = (float)0.6065306597126334;
static constexpr float CR2 = (float)(-50.0 * E_D * 0.5);
static constexpr float TH1 = 30.0f;
static constexpr float TH2 = 50.0f;

// ---------------- KA: float spikes -> x-transposed bit words ---------------
__global__ __launch_bounds__(NT)
void ka_pack(const float* __restrict__ in, unsigned* __restrict__ bitT) {
    const int gw = blockIdx.x * (NT / 64) + (threadIdx.x >> 6);
    const int ln = threadIdx.x & 63;
    const int xw = gw % XW;
    const int ny = gw / XW;                 // n*HH + y
    const float* src = in + ((size_t)ny * WW + xw * 32) * TT + ln;
    unsigned w = 0u;
#pragma unroll
    for (int x = 0; x < 32; x++) {
        const float v = src[(size_t)x * TT];
        w |= (v != 0.f) ? (1u << x) : 0u;
    }
    bitT[((size_t)ny * XW + xw) * TT + ln] = w;
}

// ---------------- L1: VALU conv1 + per-wave scan1 -> s1h -------------------
// Block: 16 output rows x 16 cols; wave wv owns rows yb..yb+3 end-to-end.
// Grid 12 x 12 x 4 = 576 blocks. LDS 68.6 KB -> 2 blocks/CU.
__global__ __launch_bounds__(NT, 2)
void l1_convscan(const unsigned* __restrict__ bitT, const float* __restrict__ w1g,
                 unsigned short* __restrict__ s1h) {
    __shared__ float ct[4][64 * 65];      // per-wave conv out [px][t], stride 65
    __shared__ uint2 tb[4][64];           // per-wave scan out bits

    const int n = blockIdx.z, ys = blockIdx.y, xs = blockIdx.x;
    const int y0 = ys * 16, x0 = xs * 16;
    const int tid = threadIdx.x;
    const int wv = tid >> 6, ln = tid & 63;
    const int yb = y0 + wv * 4;           // wave's first output row

    // Weights: uniform -> force SGPR via readfirstlane (v_fmac v,s,v legal).
    float w1r[25];
#pragma unroll
    for (int k = 0; k < 25; k++) {
        union { float f; int i; } u;
        u.f = w1g[k];
        u.i = __builtin_amdgcn_readfirstlane(u.i);
        w1r[k] = u.f;
    }

    // Window regs: 8 rows yb-2..yb+5 cover the 4 output rows' 5-row windows.
    // w20[dy] bits c=0..19 <-> gx = x0-2+c, lane = t.
    const int a = (x0 - 2) >> 5;
    const int s = (x0 - 2) & 31;
    unsigned w20[8];
#pragma unroll
    for (int dy = 0; dy < 8; dy++) {
        const int gy = yb - 2 + dy;
        unsigned wa = 0u, wb = 0u;
        if (gy >= 0 && gy < HH) {
            const unsigned* rp = bitT + ((size_t)(n * HH + gy) * XW) * TT + ln;
            if (a >= 0)     wa = rp[(size_t)a * TT];
            if (a + 1 < XW) wb = rp[(size_t)(a + 1) * TT];
        }
        w20[dy] = (wa >> s) | (wb << (32 - s));
    }

    // Conv: bit->float hoisted ONCE per window row (shared by up to 5 output
    // rows), 8-col halves. Lanes = t; px = r*16 + ch + col.
    // Per output row: l0..l4 j-ascending, ((l0+l1)+(l2+l3))+l4 — bitwise
    // identical to rounds 8-12.
#pragma unroll
    for (int h = 0; h < 2; h++) {
        const int ch = h * 8;
        float b[8][12];
#pragma unroll
        for (int k = 0; k < 8; k++)
#pragma unroll
            for (int c = 0; c < 12; c++)
                b[k][c] = (float)((w20[k] >> (ch + c)) & 1u);
#pragma unroll
        for (int r = 0; r < 4; r++) {
#pragma unroll
            for (int col = 0; col < 8; col++) {
                float l0 = b[r + 0][col] * w1r[0];
                float l1 = b[r + 1][col] * w1r[5];
                float l2 = b[r + 2][col] * w1r[10];
                float l3 = b[r + 3][col] * w1r[15];
                float l4 = b[r + 4][col] * w1r[20];
#pragma unroll
                for (int j = 1; j < 5; j++) {
                    l0 += b[r + 0][col + j] * w1r[j];
                    l1 += b[r + 1][col + j] * w1r[5 + j];
                    l2 += b[r + 2][col + j] * w1r[10 + j];
                    l3 += b[r + 3][col + j] * w1r[15 + j];
                    l4 += b[r + 4][col + j] * w1r[20 + j];
                }
                ct[wv][(r * 16 + ch + col) * 65 + ln] = ((l0 + l1) + (l2 + l3)) + l4;
            }
        }
    }
    __syncthreads();

    // Scan: EVERY wave, lane = px over its own 64 px. Ops identical r0-r12.
    {
        const int px = ln;
        float u1 = 0.f, v1 = 0.f, ur = 0.f, vr = 0.f;
        unsigned slo = 0u, shi = 0u;
#pragma unroll
        for (int tc = 0; tc < TT; tc += 8) {
            float c8[8];
#pragma unroll
            for (int j = 0; j < 8; j++) c8[j] = ct[wv][px * 65 + tc + j];
#pragma unroll
            for (int j = 0; j < 8; j++) {
                v1 = D1 * (v1 + u1);
                const float p = CP1 * v1;
                u1 = D1 * u1 + c8[j];
                vr = DR1 * (vr + ur);
                const float m = p + CR1 * vr;
                const bool sp = (m >= TH1);
                ur = DR1 * ur + (sp ? 1.f : 0.f);
                const unsigned bit = sp ? (1u << ((tc + j) & 31)) : 0u;
                if (tc < 32) slo |= bit;
                else         shi |= bit;
            }
        }
        tb[wv][px] = make_uint2(slo, shi);
    }
    __syncthreads();

    // Transpose: wave wv -> its 4 y-rows; lanes = t, 4 coalesced stores.
#pragma unroll
    for (int r = 0; r < 4; r++) {
        unsigned h = 0u;
#pragma unroll
        for (int x = 0; x < 16; x++) {
            const uint2 bb = tb[wv][r * 16 + x];     // LDS broadcast
            const unsigned w = (ln < 32) ? bb.x : bb.y;
            h |= ((w >> (ln & 31)) & 1u) << x;
        }
        s1h[((size_t)(n * HH + yb + r) * XH + xs) * TT + ln] = (unsigned short)h;
    }
}

// ---------------- L2: conv2 patterns + lut3 per-wave scan2 -> float out ----
// Block: 16 output rows x 16 cols; wave wv owns rows yb..yb+3 end-to-end.
// Grid 12 x 12 x 4 = 576 blocks. LDS 37.9 KB -> 4 blocks/CU.
__global__ __launch_bounds__(NT, 4)
void l2_convscan(const unsigned short* __restrict__ s1h, const float* __restrict__ w2g,
                 float* __restrict__ out) {
    __shared__ float          lut3[512];
    __shared__ unsigned short ptile[4][64 * 66];   // per-wave patterns [px][t]
    __shared__ uint2          tb[4][64];

    const int n = blockIdx.z, ys = blockIdx.y, xs = blockIdx.x;
    const int y0 = ys * 16;
    const int tid = threadIdx.x;
    const int wv = tid >> 6, ln = tid & 63;
    const int yb = y0 + wv * 4;

    // lut3[e] = (l0+l1)+l2, each lk in j-order -> bitwise = rounds 5-12.
#pragma unroll
    for (int e = tid; e < 512; e += NT) {
        float l0 = 0.f, l1 = 0.f, l2 = 0.f;
#pragma unroll
        for (int j = 0; j < 3; j++) {
            if ((e >> j) & 1)       l0 += w2g[j];
            if ((e >> (3 + j)) & 1) l1 += w2g[3 + j];
            if ((e >> (6 + j)) & 1) l2 += w2g[6 + j];
        }
        lut3[e] = (l0 + l1) + l2;
    }

    // Window regs: 6 rows yb-1..yb+4 cover the 4 output rows' 3-row windows.
    unsigned w18[6];
#pragma unroll
    for (int dy = 0; dy < 6; dy++) {
        const int gy = yb - 1 + dy;
        unsigned hm = 0u, h0 = 0u, hp = 0u;
        if (gy >= 0 && gy < HH) {
            const unsigned short* rp = s1h + ((size_t)(n * HH + gy) * XH) * TT + ln;
            if (xs > 0)      hm = rp[(size_t)(xs - 1) * TT];
            h0 = rp[(size_t)xs * TT];
            if (xs + 1 < XH) hp = rp[(size_t)(xs + 1) * TT];
        }
        w18[dy] = (hm >> 15) | (h0 << 1) | ((hp & 1u) << 17);
    }
    __syncthreads();                                // lut3 complete

    // Patterns (registers only): px = r*16 + col; row yb+r uses w18[r..r+2].
#pragma unroll
    for (int r = 0; r < 4; r++)
#pragma unroll
        for (int col = 0; col < 16; col++) {
            const unsigned pat = ((w18[r + 0] >> col) & 7)
                               | (((w18[r + 1] >> col) & 7) << 3)
                               | (((w18[r + 2] >> col) & 7) << 6);
            ptile[wv][(r * 16 + col) * 66 + ln] = (unsigned short)pat;
        }
    __syncthreads();

    // Scan: EVERY wave, lane = px, one batched lut3 gather per t (r8-r12).
    {
        const int px = ln;
        const unsigned* pp = (const unsigned*)(&ptile[wv][px * 66]); // 2 pats/word
        float u2 = 0.f, v2 = 0.f, ur2 = 0.f, vr2 = 0.f;
        unsigned olo = 0u, ohi = 0u;
#pragma unroll
        for (int tc = 0; tc < TT; tc += 8) {
            unsigned q[4];
#pragma unroll
            for (int k = 0; k < 4; k++) q[k] = pp[tc / 2 + k];
            float l[8];
#pragma unroll
            for (int k = 0; k < 4; k++) {
                l[2 * k + 0] = lut3[q[k] & 0x1ffu];
                l[2 * k + 1] = lut3[(q[k] >> 16) & 0x1ffu];
            }
#pragma unroll
            for (int j = 0; j < 8; j++) {
                v2 = D2 * (v2 + u2);
                const float p = CP2 * v2;
                u2 = D2 * u2 + l[j];
                vr2 = DR2 * (vr2 + ur2);
                const float m = p + CR2 * vr2;
                const bool sp = (m >= TH2);
                ur2 = DR2 * ur2 + (sp ? 1.f : 0.f);
                const unsigned bit = sp ? (1u << ((tc + j) & 31)) : 0u;
                if (tc < 32) olo |= bit;
                else         ohi |= bit;
            }
        }
        tb[wv][px] = make_uint2(olo, ohi);
    }
    __syncthreads();

    // Epilogue: wave wv -> its 4 y-rows; 64 coalesced 256B stores.
    const int sh = ln & 31;
#pragma unroll
    for (int r = 0; r < 4; r++)
#pragma unroll
        for (int k = 0; k < 16; k++) {
            const uint2 bb = tb[wv][r * 16 + k];     // LDS broadcast
            const unsigned w = (ln < 32) ? bb.x : bb.y;
            out[((size_t)(n * HH + yb + r) * WW + xs * 16 + k) * TT + ln] =
                (float)((w >> sh) & 1u);
        }
}

extern "C" void kernel_launch(void* const* d_in, const int* in_sizes, int n_in,
                              void* d_out, int out_size, void* d_ws, size_t ws_size,
                              hipStream_t stream) {
    const float* in = (const float*)d_in[0];   // (4,1,192,192,64) f32 spikes
    const float* w1 = (const float*)d_in[1];   // (1,1,5,5)
    const float* w2 = (const float*)d_in[2];   // (1,1,3,3)
    float* out = (float*)d_out;                // (4,1,192,192,64) f32 spikes

    char* ws = (char*)d_ws;
    unsigned*       bitT = (unsigned*)ws;                        // 1.18 MB
    unsigned short* s1h  = (unsigned short*)(ws + (2ull << 20)); // 1.18 MB

    const int ka_blocks = (NIMG * HH * XW) / (NT / 64);          // 1152
    dim3 cgrid(WW / 16, HH / 16, NIMG);                          // 12 x 12 x 4
    ka_pack    <<<ka_blocks, NT, 0, stream>>>(in, bitT);
    l1_convscan<<<cgrid, NT, 0, stream>>>(bitT, w1, s1h);
    l2_convscan<<<cgrid, NT, 0, stream>>>(s1h, w2, out);
}

// Round 4
// 112.758 us; speedup vs baseline: 1.0601x; 1.0601x over previous
//
#include <hip/hip_runtime.h>

// SLAYER 2-layer SNN, MI355X. Round-14 (R3): revert to R1/round-12 structure.
// R2 post-mortem: wave-parallel scan (16-row blocks, 68.6KB LDS) REGRESSED
// +4.2us — the 1-wave scan was already hidden by 8-blocks/CU cross-block
// overlap (m114 implicit-overlap); R2 cut co-residency to 2 blocks/CU and
// lost the hiding. Evidence across 4 structural variants: dur_us 114.9-119.5
// (+-2%) while per-iteration harness resets (256MiB poison fill @42us, 80%
// HBM + dozens of tiny resets) dominate; kernels ~22-27us by issue/BW
// arithmetic at full occupancy. This file = best-verified kernel (115.3us):
//   KA: floats -> bitT[y][xw][t]  (1152 blocks, streaming, proven)
//   L1: window regs from bitT -> hoisted-cvt VALU conv1 (8 blocks/CU) ->
//       ct LDS -> scan1 (1 wave, hidden by co-resident blocks) -> transpose
//       -> s1h halfwords                                    [2304 blocks]
//   L2: 3 halfwords -> 9-bit patterns (regs) -> ptile LDS -> scan2
//       (lut3[512], batched 1 gather/px.t) -> coalesced float out [2304 blocks]
// All float chains bitwise-identical to rounds 8-12. absmax == 0 every round.

#define HH   192
#define WW   192
#define NIMG 4
#define TT   64
#define NT   256
#define XW   6     // uint32 x-words per image row
#define XH   12    // 16-bit x-halfwords per image row

#define E_D 2.718281828459045
static constexpr float D1  = (float)0.36787944117144233;   // exp(-1/1)
static constexpr float CP1 = (float)(E_D);
static constexpr float DR1 = (float)0.36787944117144233;
static constexpr float CR1 = (float)(-30.0 * E_D);
static constexpr float D2  = (float)0.6065306597126334;    // exp(-1/2)
static constexpr float CP2 = (float)(E_D * 0.5);
static constexpr float DR2 = (float)0.6065306597126334;
static constexpr float CR2 = (float)(-50.0 * E_D * 0.5);
static constexpr float TH1 = 30.0f;
static constexpr float TH2 = 50.0f;

// ---------------- KA: float spikes -> x-transposed bit words ---------------
__global__ __launch_bounds__(NT)
void ka_pack(const float* __restrict__ in, unsigned* __restrict__ bitT) {
    const int gw = blockIdx.x * (NT / 64) + (threadIdx.x >> 6);
    const int ln = threadIdx.x & 63;
    const int xw = gw % XW;
    const int ny = gw / XW;                 // n*HH + y
    const float* src = in + ((size_t)ny * WW + xw * 32) * TT + ln;
    unsigned w = 0u;
#pragma unroll
    for (int x = 0; x < 32; x++) {
        const float v = src[(size_t)x * TT];
        w |= (v != 0.f) ? (1u << x) : 0u;
    }
    bitT[((size_t)ny * XW + xw) * TT + ln] = w;
}

// ---------------- L1: VALU conv1 + scan1 -> s1h ----------------------------
// Block: 4 output rows x 16 cols (64 px). Grid 12 x 48 x 4 = 2304 blocks.
__global__ __launch_bounds__(NT, 8)
void l1_convscan(const unsigned* __restrict__ bitT, const float* __restrict__ w1g,
                 unsigned short* __restrict__ s1h) {
    __shared__ float ct[64 * 65];         // conv out [px][t], stride 65
    __shared__ uint2 tb[64];

    const int n = blockIdx.z, ys = blockIdx.y, xs = blockIdx.x;
    const int y0 = ys * 4, x0 = xs * 16;
    const int tid = threadIdx.x;
    const int wv = tid >> 6, ln = tid & 63;

    // Weights: uniform -> force SGPR via readfirstlane (v_fmac v,s,v legal).
    float w1r[25];
#pragma unroll
    for (int k = 0; k < 25; k++) {
        union { float f; int i; } u;
        u.f = w1g[k];
        u.i = __builtin_amdgcn_readfirstlane(u.i);
        w1r[k] = u.f;
    }

    // Window regs from global bitT (L2-resident): wave wv -> output row y0+wv.
    // w20[dy] bits c=0..19 <-> gx = x0-2+c, lane = t. Shift s in {30,14}.
    const int a = (x0 - 2) >> 5;
    const int s = (x0 - 2) & 31;
    const int gyb = y0 + wv;
    unsigned w20[5];
#pragma unroll
    for (int dy = 0; dy < 5; dy++) {
        const int gy = gyb - 2 + dy;
        unsigned wa = 0u, wb = 0u;
        if (gy >= 0 && gy < HH) {
            const unsigned* rp = bitT + ((size_t)(n * HH + gy) * XW) * TT + ln;
            if (a >= 0)     wa = rp[(size_t)a * TT];
            if (a + 1 < XW) wb = rp[(size_t)(a + 1) * TT];
        }
        w20[dy] = (wa >> s) | (wb << (32 - s));
    }

    // Conv: hoisted bit->float per row (bfe+cvt once per bit, shared by 5
    // cols), 8-col halves to bound VGPR. Lanes = t; px = wv*16 + ch + col.
    // Addition order == rounds 8-13 bitwise.
#define CONV_ROW(DY, WBASE, STMT)                                         \
    {                                                                     \
        float b[12];                                                      \
        _Pragma("unroll")                                                 \
        for (int c = 0; c < 12; c++)                                      \
            b[c] = (float)((w20[DY] >> (ch + c)) & 1u);                   \
        _Pragma("unroll")                                                 \
        for (int col = 0; col < 8; col++) {                               \
            float t = b[col] * w1r[WBASE];                                \
            _Pragma("unroll")                                             \
            for (int j = 1; j < 5; j++) t += b[col + j] * w1r[WBASE + j]; \
            STMT;                                                         \
        }                                                                 \
    }

#pragma unroll
    for (int h = 0; h < 2; h++) {
        const int ch = h * 8;
        float m01[8], m23[8];
        CONV_ROW(0, 0,  m01[col] = t)
        CONV_ROW(1, 5,  m01[col] += t)
        CONV_ROW(2, 10, m23[col] = t)
        CONV_ROW(3, 15, m23[col] += t)
        CONV_ROW(4, 20, ct[(wv * 16 + ch + col) * 65 + ln] = (m01[col] + m23[col]) + t)
    }
#undef CONV_ROW
    __syncthreads();

    // Scan: 1 wave, lane = px (64 px). Op-identical to rounds 0-13. Hidden by
    // 8 co-resident blocks/CU (evidence: R2's all-wave scan at 2 blocks/CU
    // regressed).
    if (tid < 64) {
        const int px = tid;
        float u1 = 0.f, v1 = 0.f, ur = 0.f, vr = 0.f;
        unsigned slo = 0u, shi = 0u;
#pragma unroll
        for (int tc = 0; tc < TT; tc += 8) {
            float c8[8];
#pragma unroll
            for (int j = 0; j < 8; j++) c8[j] = ct[px * 65 + tc + j];
#pragma unroll
            for (int j = 0; j < 8; j++) {
                v1 = D1 * (v1 + u1);
                const float p = CP1 * v1;
                u1 = D1 * u1 + c8[j];
                vr = DR1 * (vr + ur);
                const float m = p + CR1 * vr;
                const bool sp = (m >= TH1);
                ur = DR1 * ur + (sp ? 1.f : 0.f);
                const unsigned bit = sp ? (1u << ((tc + j) & 31)) : 0u;
                if (tc < 32) slo |= bit;
                else         shi |= bit;
            }
        }
        tb[px] = make_uint2(slo, shi);
    }
    __syncthreads();

    // Transpose: wave wv -> y-row y0+wv; lanes = t, one coalesced store.
    {
        unsigned h = 0u;
#pragma unroll
        for (int x = 0; x < 16; x++) {
            const uint2 b = tb[wv * 16 + x];         // LDS broadcast
            const unsigned w = (ln < 32) ? b.x : b.y;
            h |= ((w >> (ln & 31)) & 1u) << x;
        }
        s1h[((size_t)(n * HH + gyb) * XH + xs) * TT + ln] = (unsigned short)h;
    }
}

// ---------------- L2: conv2 patterns + lut3 scan2 -> float out -------------
// Block: 4 output rows x 16 cols (64 px). Grid 12 x 48 x 4 = 2304 blocks.
__global__ __launch_bounds__(NT, 8)
void l2_convscan(const unsigned short* __restrict__ s1h, const float* __restrict__ w2g,
                 float* __restrict__ out) {
    __shared__ float          lut3[512];
    __shared__ unsigned short ptile[64 * 66];   // 9-bit patterns [px][t]
    __shared__ uint2          tb[64];

    const int n = blockIdx.z, ys = blockIdx.y, xs = blockIdx.x;
    const int y0 = ys * 4;
    const int tid = threadIdx.x;
    const int wv = tid >> 6, ln = tid & 63;

    // lut3[e] = (l0+l1)+l2, each lk in j-order -> bitwise = rounds 5-13.
#pragma unroll
    for (int e = tid; e < 512; e += NT) {
        float l0 = 0.f, l1 = 0.f, l2 = 0.f;
#pragma unroll
        for (int j = 0; j < 3; j++) {
            if ((e >> j) & 1)       l0 += w2g[j];
            if ((e >> (3 + j)) & 1) l1 += w2g[3 + j];
            if ((e >> (6 + j)) & 1) l2 += w2g[6 + j];
        }
        lut3[e] = (l0 + l1) + l2;
    }

    // Window regs: wave wv -> output row y0+wv; 9 halfword loads, lane = t.
    const int gyb = y0 + wv;
    unsigned w18[3];
#pragma unroll
    for (int dy = 0; dy < 3; dy++) {
        const int gy = gyb - 1 + dy;
        unsigned hm = 0u, h0 = 0u, hp = 0u;
        if (gy >= 0 && gy < HH) {
            const unsigned short* rp = s1h + ((size_t)(n * HH + gy) * XH) * TT + ln;
            if (xs > 0)      hm = rp[(size_t)(xs - 1) * TT];
            h0 = rp[(size_t)xs * TT];
            if (xs + 1 < XH) hp = rp[(size_t)(xs + 1) * TT];
        }
        w18[dy] = (hm >> 15) | (h0 << 1) | ((hp & 1u) << 17);
    }
    __syncthreads();

    // Patterns (registers only): px = wv*16 + col.
#pragma unroll
    for (int col = 0; col < 16; col++) {
        const unsigned pat = ((w18[0] >> col) & 7)
                           | (((w18[1] >> col) & 7) << 3)
                           | (((w18[2] >> col) & 7) << 6);
        ptile[(wv * 16 + col) * 66 + ln] = (unsigned short)pat;
    }
    __syncthreads();

    // Scan: 1 wave, lane = px, one batched lut3 gather per t (r8-r13).
    if (tid < 64) {
        const int px = tid;
        const unsigned* pp = (const unsigned*)(ptile + px * 66);  // 2 pats/word
        float u2 = 0.f, v2 = 0.f, ur2 = 0.f, vr2 = 0.f;
        unsigned olo = 0u, ohi = 0u;
#pragma unroll
        for (int tc = 0; tc < TT; tc += 8) {
            unsigned q[4];
#pragma unroll
            for (int k = 0; k < 4; k++) q[k] = pp[tc / 2 + k];
            float l[8];
#pragma unroll
            for (int k = 0; k < 4; k++) {
                l[2 * k + 0] = lut3[q[k] & 0x1ffu];
                l[2 * k + 1] = lut3[(q[k] >> 16) & 0x1ffu];
            }
#pragma unroll
            for (int j = 0; j < 8; j++) {
                v2 = D2 * (v2 + u2);
                const float p = CP2 * v2;
                u2 = D2 * u2 + l[j];
                vr2 = DR2 * (vr2 + ur2);
                const float m = p + CR2 * vr2;
                const bool sp = (m >= TH2);
                ur2 = DR2 * ur2 + (sp ? 1.f : 0.f);
                const unsigned bit = sp ? (1u << ((tc + j) & 31)) : 0u;
                if (tc < 32) olo |= bit;
                else         ohi |= bit;
            }
        }
        tb[px] = make_uint2(olo, ohi);
    }
    __syncthreads();

    // Epilogue: wave wv -> output row y0+wv; 16 coalesced 256B stores.
    const int sh = ln & 31;
#pragma unroll
    for (int k = 0; k < 16; k++) {
        const uint2 b = tb[wv * 16 + k];             // LDS broadcast
        const unsigned w = (ln < 32) ? b.x : b.y;
        out[((size_t)(n * HH + gyb) * WW + xs * 16 + k) * TT + ln] =
            (float)((w >> sh) & 1u);
    }
}

extern "C" void kernel_launch(void* const* d_in, const int* in_sizes, int n_in,
                              void* d_out, int out_size, void* d_ws, size_t ws_size,
                              hipStream_t stream) {
    const float* in = (const float*)d_in[0];   // (4,1,192,192,64) f32 spikes
    const float* w1 = (const float*)d_in[1];   // (1,1,5,5)
    const float* w2 = (const float*)d_in[2];   // (1,1,3,3)
    float* out = (float*)d_out;                // (4,1,192,192,64) f32 spikes

    char* ws = (char*)d_ws;
    unsigned*       bitT = (unsigned*)ws;                        // 1.18 MB
    unsigned short* s1h  = (unsigned short*)(ws + (2ull << 20)); // 1.18 MB

    const int ka_blocks = (NIMG * HH * XW) / (NT / 64);          // 1152
    dim3 cgrid(WW / 16, HH / 4, NIMG);                           // 12 x 48 x 4
    ka_pack    <<<ka_blocks, NT, 0, stream>>>(in, bitT);
    l1_convscan<<<cgrid, NT, 0, stream>>>(bitT, w1, s1h);
    l2_convscan<<<cgrid, NT, 0, stream>>>(s1h, w2, out);
}